// Round 6
// baseline (227.408 us; speedup 1.0000x reference)
//
#include <hip/hip_runtime.h>

// x [B, NF, T] f32, durations [B, N] int32 -> out [B, NF, N] f32
#define BB 64
#define NF 64
#define TT 8192
#define NN 1024
#define GR 8                        // granule = 8 floats
#define NG (TT / GR)                // 1024 granules per row
#define ROWS (BB * NF)              // 4096
#define PAD(c) ((c) + ((c) >> 3))   // padded LDS index, ~2-way max (free)

// K1: pure stream. One thread per granule: 2x float4 loads, reduce in regs,
// one coalesced float2 (sum, nonzero-count) store. No LDS, no barriers ->
// HBM never idles.
__global__ __launch_bounds__(256) void reduce_kernel(const float* __restrict__ x,
                                                     float2* __restrict__ gsc) {
    const size_t tid = (size_t)blockIdx.x * 256 + threadIdx.x;
    const float4* xp = (const float4*)(x + tid * GR);
    const float4 a = xp[0], b = xp[1];
    const float s = ((a.x + a.y) + (a.z + a.w)) + ((b.x + b.y) + (b.z + b.w));
    const float c = ((a.x != 0.f) + (a.y != 0.f) + (a.z != 0.f) + (a.w != 0.f))
                  + ((b.x != 0.f) + (b.y != 0.f) + (b.z != 0.f) + (b.w != 0.f));
    gsc[tid] = make_float2(s, c);
}

// K2: per-row finalize. Duration scan (L2-hot), block scan of 1024 granule
// (sum,count) pairs, boundary eval with <=7-elem remainder from global x
// (L3-resident), token means.
__global__ __launch_bounds__(256) void finalize_kernel(const float* __restrict__ x,
                                                       const int* __restrict__ dur,
                                                       const float2* __restrict__ gsc,
                                                       float* __restrict__ out) {
    const int row  = blockIdx.x;          // b*NF + nf
    const int bat  = row >> 6;            // NF = 64
    const int t    = threadIdx.x;
    const int lane = t & 63;
    const int w    = t >> 6;

    __shared__ int   bs[NN + 1];          // boundaries
    __shared__ float S[PAD(NG) + 1];      // exclusive granule-sum prefix (+ total)
    __shared__ float C[PAD(NG) + 1];      // exclusive granule-count prefix (+ total)
    __shared__ float P[NN + 1];           // prefix sum at boundaries
    __shared__ float Kc[NN + 1];          // prefix count at boundaries
    __shared__ float wsf[4];
    __shared__ float wcf[4];
    __shared__ int   wsi[4];

    // ---- duration scan: 4 per thread + wave shfl + wave combine ----
    const int4 d4 = ((const int4*)(dur + bat * NN))[t];
    const int i0 = d4.x, i1 = i0 + d4.y, i2 = i1 + d4.z, i3 = i2 + d4.w;
    int wsum = i3;
#pragma unroll
    for (int d = 1; d < 64; d <<= 1) {
        int u = __shfl_up(wsum, d, 64);
        if (lane >= d) wsum += u;
    }
    if (lane == 63) wsi[w] = wsum;
    __syncthreads();
    int boff = 0;
#pragma unroll
    for (int i = 0; i < 4; ++i) if (i < w) boff += wsi[i];
    const int eb = boff + wsum - i3;
    bs[4 * t + 1] = eb + i0;
    bs[4 * t + 2] = eb + i1;
    bs[4 * t + 3] = eb + i2;
    bs[4 * t + 4] = eb + i3;
    if (t == 0) bs[0] = 0;

    // ---- granule scan: thread owns granules 4t..4t+3 ----
    const float4* grow = (const float4*)(gsc + (size_t)row * NG);
    const float4 ga = grow[2 * t];        // (s0,c0,s1,c1)
    const float4 gb = grow[2 * t + 1];    // (s2,c2,s3,c3)
    float sv[4], cv[4];
    sv[0] = ga.x;         cv[0] = ga.y;
    sv[1] = sv[0] + ga.z; cv[1] = cv[0] + ga.w;
    sv[2] = sv[1] + gb.x; cv[2] = cv[1] + gb.y;
    sv[3] = sv[2] + gb.z; cv[3] = cv[2] + gb.w;
    float ws = sv[3], wc = cv[3];
#pragma unroll
    for (int d = 1; d < 64; d <<= 1) {
        float uf = __shfl_up(ws, d, 64);
        float uc = __shfl_up(wc, d, 64);
        if (lane >= d) { ws += uf; wc += uc; }
    }
    if (lane == 63) { wsf[w] = ws; wcf[w] = wc; }
    __syncthreads();
    float woff = 0.f, coff = 0.f;
#pragma unroll
    for (int i = 0; i < 4; ++i) if (i < w) { woff += wsf[i]; coff += wcf[i]; }
    const float fbase = woff + (ws - sv[3]);   // exclusive base for granule 4t
    const float cbase = coff + (wc - cv[3]);
#pragma unroll
    for (int j = 0; j < 4; ++j) {
        const int c = 4 * t + j;
        S[PAD(c)] = fbase + (j ? sv[j - 1] : 0.f);
        C[PAD(c)] = cbase + (j ? cv[j - 1] : 0.f);
    }
    if (t == 255) { S[PAD(NG)] = woff + ws; C[PAD(NG)] = coff + wc; }
    __syncthreads();

    // ---- boundary eval: prefix at p = granule prefix + <=7-elem remainder ----
    const float* xrow = x + (size_t)row * TT;
    for (int i = t; i <= NN; i += 256) {
        const int p = bs[i];              // in [0, T]
        const int g = p >> 3, r = p & 7;
        float part = 0.f, pc = 0.f;
        if (r) {
            const float* xb = xrow + (p & ~7);
            const float4 v = *(const float4*)xb;
            part = v.x; pc = (v.x != 0.f);
            if (r > 1) { part += v.y; pc += (v.y != 0.f); }
            if (r > 2) { part += v.z; pc += (v.z != 0.f); }
            if (r > 3) { part += v.w; pc += (v.w != 0.f); }
            if (r > 4) {
                const float4 u = *(const float4*)(xb + 4);
                part += u.x; pc += (u.x != 0.f);
                if (r > 5) { part += u.y; pc += (u.y != 0.f); }
                if (r > 6) { part += u.z; pc += (u.z != 0.f); }
            }
        }
        P[i]  = S[PAD(g)] + part;         // p==T -> g==NG -> grand-total, r==0
        Kc[i] = C[PAD(g)] + pc;
    }
    __syncthreads();

    // ---- token means, coalesced ----
    float* orow = out + (size_t)row * NN;
#pragma unroll
    for (int k = 0; k < NN / 256; ++k) {
        const int n = t + (k << 8);
        const float s = P[n + 1] - P[n];
        const float c = Kc[n + 1] - Kc[n];
        orow[n] = (c != 0.f) ? (s / c) : 0.f;
    }
}

extern "C" void kernel_launch(void* const* d_in, const int* in_sizes, int n_in,
                              void* d_out, int out_size, void* d_ws, size_t ws_size,
                              hipStream_t stream) {
    const float* x   = (const float*)d_in[0];
    const int*   dur = (const int*)d_in[1];
    float*       out = (float*)d_out;
    float2*      gsc = (float2*)d_ws;     // 4096*1024*8B = 33.6 MB scratch

    reduce_kernel<<<ROWS * NG / 256, 256, 0, stream>>>(x, gsc);
    finalize_kernel<<<ROWS, 256, 0, stream>>>(x, dur, gsc, out);
}

// Round 7
// 193.234 us; speedup vs baseline: 1.1769x; 1.1769x over previous
//
#include <hip/hip_runtime.h>

// x [B, NF, T] f32, durations [B, N] int32 -> out [B, NF, N] f32
// out[b,f,n] = mean of nonzero x[b,f,ts..te) (0 if no nonzeros), ts/te from cumsum(durations)
#define BB 64
#define NF 64
#define TT 8192
#define NN 1024
#define NC (TT / 4)                 // 2048 chunks of 4 floats
#define PAD(c) ((c) + ((c) >> 3))   // conflict-free-ish padded index

// One block per (b,nf) row; one fused kernel, 4 barriers, no scratch:
//  - issue 8x float4 row loads + int4 dur load into regs (in flight during P0)
//  - P0: duration shfl-scan -> this thread's 5 token boundaries IN REGISTERS
//  - stage regs -> raw LDS; chunk (sum,count) computed FROM REGS -> padded LDS
//  - block scan of 2048 (sum,count) pairs (8/thread + wave shfl + wave combine)
//  - eval 5 prefixes (padded read + <=3-elem remainder from raw LDS) -> 4 means
// LDS ~50.4 KB -> 3 blocks/CU (12 waves/CU).
__global__ __launch_bounds__(256) void fused_kernel(const float* __restrict__ x,
                                                    const int* __restrict__ dur,
                                                    float* __restrict__ out) {
    const int row  = blockIdx.x;          // b*NF + nf
    const int bat  = row >> 6;            // NF = 64
    const int t    = threadIdx.x;
    const int lane = t & 63;
    const int w    = t >> 6;

    __shared__ float  raw[TT];            // 32 KB raw row (linear)
    __shared__ float2 SC[PAD(NC) + 1];    // 18.4 KB (sum,count) per chunk -> exclusive scan
    __shared__ int    wsi[4];
    __shared__ float  wsf[4], wcf[4];

    // ---- issue all global loads first (stay in flight through P0) ----
    const float4* __restrict__ xv = (const float4*)(x + (size_t)row * TT);
    float4 stage[8];
#pragma unroll
    for (int k = 0; k < 8; ++k) stage[k] = xv[t + (k << 8)];
    const int4 d4 = ((const int4*)(dur + bat * NN))[t];

    // ---- P0: duration scan -> boundaries in registers ----
    const int i0 = d4.x, i1 = i0 + d4.y, i2 = i1 + d4.z, i3 = i2 + d4.w;
    int wsum = i3;
#pragma unroll
    for (int d = 1; d < 64; d <<= 1) {
        int u = __shfl_up(wsum, d, 64);
        if (lane >= d) wsum += u;
    }
    if (lane == 63) wsi[w] = wsum;
    __syncthreads();
    int boff = 0;
#pragma unroll
    for (int i = 0; i < 4; ++i) if (i < w) boff += wsi[i];
    const int eb = boff + wsum - i3;      // exclusive base for this thread's 4 tokens
    const int bnd[5] = { eb, eb + i0, eb + i1, eb + i2, eb + i3 };

    // ---- stage -> raw LDS; chunk sums/counts from registers ----
#pragma unroll
    for (int k = 0; k < 8; ++k) {
        const int c = t + (k << 8);       // coalesced 16B LDS writes, conflict-free
        ((float4*)raw)[c] = stage[k];
        const float4 v = stage[k];
        SC[PAD(c)] = make_float2(v.x + v.y + v.z + v.w,
                                 (v.x != 0.f) + (v.y != 0.f) + (v.z != 0.f) + (v.w != 0.f));
    }
    __syncthreads();

    // ---- block exclusive scan over 2048 chunks; thread owns [8t, 8t+8) ----
    float sv[8], cv[8];
    float fs = 0.f, cs = 0.f;
#pragma unroll
    for (int j = 0; j < 8; ++j) {
        const float2 p = SC[PAD((t << 3) + j)];   // PAD = 9t+j
        fs += p.x; cs += p.y;
        sv[j] = fs; cv[j] = cs;           // within-thread inclusive
    }
    float ws = fs, wc = cs;
#pragma unroll
    for (int d = 1; d < 64; d <<= 1) {
        float uf = __shfl_up(ws, d, 64);
        float uc = __shfl_up(wc, d, 64);
        if (lane >= d) { ws += uf; wc += uc; }
    }
    if (lane == 63) { wsf[w] = ws; wcf[w] = wc; }
    __syncthreads();
    float woff = 0.f, coff = 0.f;
#pragma unroll
    for (int i = 0; i < 4; ++i) if (i < w) { woff += wsf[i]; coff += wcf[i]; }
    const float fb = woff + (ws - fs);    // exclusive base for chunk 8t
    const float cb = coff + (wc - cs);
#pragma unroll
    for (int j = 0; j < 8; ++j) {
        SC[PAD((t << 3) + j)] = make_float2(fb + (j ? sv[j - 1] : 0.f),
                                            cb + (j ? cv[j - 1] : 0.f));
    }
    if (t == 255) SC[PAD(NC)] = make_float2(woff + ws, coff + wc);  // grand total (p==T)
    __syncthreads();

    // ---- eval 5 boundary prefixes -> 4 token means (all in regs) ----
    float ps[5], pk[5];
#pragma unroll
    for (int j = 0; j < 5; ++j) {
        const int p = bnd[j];             // in [0, T]
        const int g = p >> 2, r = p & 3;
        const float2 pre = SC[PAD(g)];    // p==T -> g==NC -> grand-total slot, r==0
        float s = pre.x, c = pre.y;
        if (r) {
            const float4 v = ((const float4*)raw)[g];
            s += v.x; c += (v.x != 0.f);
            if (r > 1) { s += v.y; c += (v.y != 0.f); }
            if (r > 2) { s += v.z; c += (v.z != 0.f); }
        }
        ps[j] = s; pk[j] = c;
    }
    float4 o;
    {
        const float s0 = ps[1] - ps[0], c0 = pk[1] - pk[0];
        const float s1 = ps[2] - ps[1], c1 = pk[2] - pk[1];
        const float s2 = ps[3] - ps[2], c2 = pk[3] - pk[2];
        const float s3 = ps[4] - ps[3], c3 = pk[4] - pk[3];
        o.x = (c0 != 0.f) ? s0 / c0 : 0.f;
        o.y = (c1 != 0.f) ? s1 / c1 : 0.f;
        o.z = (c2 != 0.f) ? s2 / c2 : 0.f;
        o.w = (c3 != 0.f) ? s3 / c3 : 0.f;
    }
    ((float4*)(out + (size_t)row * NN))[t] = o;   // tokens 4t..4t+3, coalesced
}

extern "C" void kernel_launch(void* const* d_in, const int* in_sizes, int n_in,
                              void* d_out, int out_size, void* d_ws, size_t ws_size,
                              hipStream_t stream) {
    const float* x   = (const float*)d_in[0];
    const int*   dur = (const int*)d_in[1];
    float*       out = (float*)d_out;
    fused_kernel<<<BB * NF, 256, 0, stream>>>(x, dur, out);
}